// Round 10
// baseline (134.431 us; speedup 1.0000x reference)
//
#include <hip/hip_runtime.h>

typedef _Float16 half8 __attribute__((ext_vector_type(8)));
typedef _Float16 half4 __attribute__((ext_vector_type(4)));
typedef _Float16 half2 __attribute__((ext_vector_type(2)));
typedef __fp16  fp16x2 __attribute__((ext_vector_type(2)));
typedef float f32x4 __attribute__((ext_vector_type(4)));

static __device__ __forceinline__ half2 cvt_pk(float a, float b) {
    fp16x2 r = __builtin_amdgcn_cvt_pkrtz(a, b);
    return __builtin_bit_cast(half2, r);
}
static __device__ __forceinline__ float fdot2_acc(half2 a, half2 b, float c) {
    return __builtin_amdgcn_fdot2(__builtin_bit_cast(fp16x2, a),
                                  __builtin_bit_cast(fp16x2, b), c, false);
}

// B=8, L1=L2=1024, D_IN=768, H=12, DK=DV=64, M=B*L=8192

// ---------------------------------------------------------------------------
// One-time W transpose+convert: Wt[z][n][k] fp16 = W_z[k][n] fp32, z in {q,k,v}
// ---------------------------------------------------------------------------
__global__ __launch_bounds__(256)
void wtrans_kernel(const float* __restrict__ Wq, const float* __restrict__ Wk,
                   const float* __restrict__ Wv, _Float16* __restrict__ Wt)
{
    __shared__ float t[32][33];
    const float* W = (blockIdx.z == 0) ? Wq : (blockIdx.z == 1) ? Wk : Wv;
    _Float16* dst = Wt + blockIdx.z * 768 * 768;
    const int tx = threadIdx.x & 31, ty = threadIdx.x >> 5;
    const int k0 = blockIdx.y * 32, n0 = blockIdx.x * 32;
    #pragma unroll
    for (int i = 0; i < 4; ++i)
        t[ty + 8 * i][tx] = W[(k0 + ty + 8 * i) * 768 + n0 + tx];
    __syncthreads();
    #pragma unroll
    for (int i = 0; i < 4; ++i)
        dst[(n0 + ty + 8 * i) * 768 + k0 + tx] = (_Float16)t[tx][ty + 8 * i];
}

// ---------------------------------------------------------------------------
// Projection GEMM: z=0: K = y@Wk+bk -> [8192][768]
//                  z=1: V = y@Wv+bv -> Vt [B][H*DV][L2]
//                  z=2: Q = (x@Wq+bq)*0.125 -> [8192][768]
// ---------------------------------------------------------------------------
__global__ __launch_bounds__(256)
void proj_kernel(const float* __restrict__ x, const float* __restrict__ y,
                 const _Float16* __restrict__ Wt,
                 const float* __restrict__ bk, const float* __restrict__ bv,
                 const float* __restrict__ bq,
                 _Float16* __restrict__ kout, _Float16* __restrict__ vout,
                 _Float16* __restrict__ qout)
{
    __shared__ __align__(16) char smem[34816];
    _Float16* const Alds = (_Float16*)smem;            // [128][40] padded
    _Float16* const Wlds = (_Float16*)smem + 128 * 40; // [128][40]
    _Float16* const Tlds = (_Float16*)smem;            // [128][136] epilogue

    const int tid  = threadIdx.x;
    const int lane = tid & 63;
    const int wave = tid >> 6;
    const int lr = lane & 15, lg = lane >> 4;
    const int wm = wave >> 1, wn = wave & 1;
    const int m0 = blockIdx.x * 128;
    const int n0 = blockIdx.y * 128;
    const int z  = blockIdx.z;                         // 0=K 1=V 2=Q

    const float* __restrict__ A = (z == 2) ? x : y;
    const _Float16* __restrict__ W = Wt + ((z == 2) ? 0 : (1 + z)) * 768 * 768;
    const float* __restrict__ bias = (z == 0) ? bk : (z == 1) ? bv : bq;
    const float sc = (z == 2) ? 0.125f : 1.0f;

    f32x4 acc[4][4] = {};

    const int ar   = tid >> 3;
    const int ac   = (tid & 7) * 4;
    const int wrow = tid >> 1;
    const int wcb  = (tid & 1) * 16;

    for (int kb = 0; kb < 24; ++kb) {
        #pragma unroll
        for (int i = 0; i < 4; ++i) {
            const int row = ar + 32 * i;
            const float4 v = *(const float4*)(A + (m0 + row) * 768 + kb * 32 + ac);
            half4 hh = { (_Float16)v.x, (_Float16)v.y, (_Float16)v.z, (_Float16)v.w };
            *(half4*)(Alds + row * 40 + ac) = hh;
        }
        {
            const _Float16* wtr = W + (n0 + wrow) * 768 + kb * 32 + wcb;
            *(uint4*)(Wlds + wrow * 40 + wcb)     = *(const uint4*)(wtr);
            *(uint4*)(Wlds + wrow * 40 + wcb + 8) = *(const uint4*)(wtr + 8);
        }
        __syncthreads();

        half8 af[4], bf[4];
        #pragma unroll
        for (int mt = 0; mt < 4; ++mt)
            af[mt] = *(const half8*)(Alds + (wm * 64 + mt * 16 + lr) * 40 + lg * 8);
        #pragma unroll
        for (int nt = 0; nt < 4; ++nt)
            bf[nt] = *(const half8*)(Wlds + (wn * 64 + nt * 16 + lr) * 40 + lg * 8);
        #pragma unroll
        for (int mt = 0; mt < 4; ++mt)
            #pragma unroll
            for (int nt = 0; nt < 4; ++nt)
                acc[mt][nt] = __builtin_amdgcn_mfma_f32_16x16x32_f16(af[mt], bf[nt], acc[mt][nt], 0, 0, 0);
        __syncthreads();
    }

    #pragma unroll
    for (int nt = 0; nt < 4; ++nt) {
        const int col = wn * 64 + nt * 16 + lr;
        const float bs = bias[n0 + col];
        #pragma unroll
        for (int mt = 0; mt < 4; ++mt) {
            #pragma unroll
            for (int r = 0; r < 4; ++r) {
                const int row = wm * 64 + mt * 16 + lg * 4 + r;
                const float val = (acc[mt][nt][r] + bs) * sc;
                if (z == 1) Tlds[col * 136 + row] = (_Float16)val;
                else        Tlds[row * 136 + col] = (_Float16)val;
            }
        }
    }
    __syncthreads();

    const int crow = tid >> 1;
    const int cb   = (tid & 1) * 64;
    const _Float16* lsrc = Tlds + crow * 136 + cb;
    _Float16* gdst;
    if (z == 1) {
        const int bb  = m0 >> 10;
        const int l2b = m0 & 1023;
        gdst = vout + (bb * 768 + n0 + crow) * 1024 + l2b + cb;
    } else {
        gdst = ((z == 0) ? kout : qout) + (m0 + crow) * 768 + n0 + cb;
    }
    #pragma unroll
    for (int it = 0; it < 8; ++it)
        *(uint4*)(gdst + it * 8) = *(const uint4*)(lsrc + it * 8);
}

// ---------------------------------------------------------------------------
// Fused attention, per block (q-tile=64, h, b).
// QPRE=1: Q precomputed in ws. QPRE=0: phase-1 Q projection (fallback).
// Phase 2: flash loop, KVBLK=64, double-buffered LDS (1 barrier/tile),
//          2-tile-deep register prefetch, exp2 softmax, defer-max.
// ---------------------------------------------------------------------------
template<bool QPRE>
__global__ __launch_bounds__(256)
void attn_kernel(const float* __restrict__ x, const _Float16* __restrict__ Wtq,
                 const float* __restrict__ bq, const _Float16* __restrict__ Qp,
                 const _Float16* __restrict__ K, const _Float16* __restrict__ Vt,
                 const unsigned char* __restrict__ mask,
                 float* __restrict__ out)
{
    __shared__ __align__(16) char smem[48128];
    _Float16* const KA = (_Float16*)smem;              // K buf A [64][72]
    _Float16* const KB = (_Float16*)(smem + 9216);     // K buf B
    _Float16* const VA = (_Float16*)(smem + 18432);    // V buf A
    _Float16* const VB = (_Float16*)(smem + 27648);    // V buf B
    _Float16* const QP = (_Float16*)(smem + 36864);    // Q [64][72] -> per-wave P
    _Float16* const Mh = (_Float16*)(smem + 46080);    // [1024] fp16 0/1

    const int tid  = threadIdx.x;
    const int lane = tid & 63;
    const int wave = tid >> 6;
    const int lr = lane & 15, lg = lane >> 4;
    const int q0 = blockIdx.x * 64;
    const int h  = blockIdx.y;
    const int b  = blockIdx.z;

    const int pr = tid >> 2;            // 0..63 staging row
    const int pc = (tid & 3) * 16;      // staging col (16 halves)

    const float C2 = 1.44269504f;       // log2(e)

    if constexpr (!QPRE) {
        // ---- phase 1 (fallback): Q tile projection, BK=64 ----
        const float* xbase = x + (b * 1024 + q0 + pr) * 768 + pc;
        const _Float16* wbase = Wtq + (h * 64 + pr) * 768 + pc;
        float4 xa, xb, xc_, xd;
        uint4 wa, wb;
        xa = *(const float4*)(xbase);      xb = *(const float4*)(xbase + 4);
        xc_ = *(const float4*)(xbase + 8); xd = *(const float4*)(xbase + 12);
        wa = *(const uint4*)(wbase);       wb = *(const uint4*)(wbase + 8);

        f32x4 qacc[4] = {};
        for (int kb = 0; kb < 12; ++kb) {
            __syncthreads();
            union { half2 hh[4]; half8 v; } u0, u1;
            u0.hh[0] = cvt_pk(xa.x, xa.y);   u0.hh[1] = cvt_pk(xa.z, xa.w);
            u0.hh[2] = cvt_pk(xb.x, xb.y);   u0.hh[3] = cvt_pk(xb.z, xb.w);
            u1.hh[0] = cvt_pk(xc_.x, xc_.y); u1.hh[1] = cvt_pk(xc_.z, xc_.w);
            u1.hh[2] = cvt_pk(xd.x, xd.y);   u1.hh[3] = cvt_pk(xd.z, xd.w);
            *(half8*)(KA + pr * 72 + pc)     = u0.v;
            *(half8*)(KA + pr * 72 + pc + 8) = u1.v;
            *(uint4*)(VA + pr * 72 + pc)     = wa;
            *(uint4*)(VA + pr * 72 + pc + 8) = wb;
            __syncthreads();
            if (kb < 11) {
                const float* xn = xbase + (kb + 1) * 64;
                const _Float16* wn = wbase + (kb + 1) * 64;
                xa = *(const float4*)(xn);      xb = *(const float4*)(xn + 4);
                xc_ = *(const float4*)(xn + 8); xd = *(const float4*)(xn + 12);
                wa = *(const uint4*)(wn);       wb = *(const uint4*)(wn + 8);
            }
            half8 af[2];
            af[0] = *(const half8*)(KA + (wave * 16 + lr) * 72 + lg * 8);
            af[1] = *(const half8*)(KA + (wave * 16 + lr) * 72 + 32 + lg * 8);
            __builtin_amdgcn_s_setprio(1);
            #pragma unroll
            for (int nt = 0; nt < 4; ++nt)
                #pragma unroll
                for (int s = 0; s < 2; ++s) {
                    const half8 bf = *(const half8*)(VA + (nt * 16 + lr) * 72 + s * 32 + lg * 8);
                    qacc[nt] = __builtin_amdgcn_mfma_f32_16x16x32_f16(af[s], bf, qacc[nt], 0, 0, 0);
                }
            __builtin_amdgcn_s_setprio(0);
        }
        #pragma unroll
        for (int nt = 0; nt < 4; ++nt) {
            const int d = nt * 16 + lr;
            const float bs = bq[h * 64 + d];
            #pragma unroll
            for (int r = 0; r < 4; ++r)
                QP[(wave * 16 + lg * 4 + r) * 72 + d] = (_Float16)((qacc[nt][r] + bs) * 0.125f);
        }
    }

    // fp16 multiplicative mask vector (1 = keep, 0 = masked)
    {
        const uchar4 mk = *(const uchar4*)(mask + b * 1024 + tid * 4);
        half4 mh = { mk.x ? (_Float16)0.f : (_Float16)1.f,
                     mk.y ? (_Float16)0.f : (_Float16)1.f,
                     mk.z ? (_Float16)0.f : (_Float16)1.f,
                     mk.w ? (_Float16)0.f : (_Float16)1.f };
        *(half4*)(Mh + tid * 4) = mh;
    }
    __syncthreads();

    // Q fragment (B-operand of S^T): lane holds Q[q=lr][d=32s+8lg+j], pre-scaled
    half8 qf[2];
    if constexpr (QPRE) {
        const _Float16* qrp = Qp + (b * 1024 + q0 + wave * 16 + lr) * 768 + h * 64;
        qf[0] = *(const half8*)(qrp + lg * 8);
        qf[1] = *(const half8*)(qrp + 32 + lg * 8);
    } else {
        // own-wave rows of QP, written by this wave above (no barrier needed)
        qf[0] = *(const half8*)(QP + (wave * 16 + lr) * 72 + lg * 8);
        qf[1] = *(const half8*)(QP + (wave * 16 + lr) * 72 + 32 + lg * 8);
    }

    f32x4 o[4] = {};
    float m_run = -1e30f, l_run = 0.f;
    const half2 one2 = { (_Float16)1.f, (_Float16)1.f };

    const _Float16* const Kg = K + (b * 1024 + pr) * 768 + h * 64 + pc;
    const _Float16* const Vg = Vt + (b * 768 + h * 64 + pr) * 1024 + pc;
    _Float16* const Pw = QP + wave * 1152;   // per-wave P region == own Q rows

    auto compute = [&](int kv0, const _Float16* Kb, const _Float16* Vb) {
        f32x4 st[4] = {};
        __builtin_amdgcn_s_setprio(1);
        #pragma unroll
        for (int t4 = 0; t4 < 4; ++t4)
            #pragma unroll
            for (int s = 0; s < 2; ++s) {
                const half8 a = *(const half8*)(Kb + (t4 * 16 + lr) * 72 + s * 32 + lg * 8);
                st[t4] = __builtin_amdgcn_mfma_f32_16x16x32_f16(a, qf[s], st[t4], 0, 0, 0);
            }
        __builtin_amdgcn_s_setprio(0);

        float mx = fmaxf(
            fmaxf(fmaxf(fmaxf(st[0][0], st[0][1]), fmaxf(st[0][2], st[0][3])),
                  fmaxf(fmaxf(st[1][0], st[1][1]), fmaxf(st[1][2], st[1][3]))),
            fmaxf(fmaxf(fmaxf(st[2][0], st[2][1]), fmaxf(st[2][2], st[2][3])),
                  fmaxf(fmaxf(st[3][0], st[3][1]), fmaxf(st[3][2], st[3][3]))));
        mx = fmaxf(mx, __shfl_xor(mx, 16));
        mx = fmaxf(mx, __shfl_xor(mx, 32));

        if (!__all(mx <= m_run + 8.f)) {
            const float m_new = fmaxf(m_run, mx);
            const float corr = __builtin_amdgcn_exp2f((m_run - m_new) * C2);
            l_run *= corr;
            #pragma unroll
            for (int i = 0; i < 4; ++i) o[i] *= corr;
            m_run = m_new;
        }
        const float nb = -m_run * C2;

        float ps = 0.f;
        #pragma unroll
        for (int t4 = 0; t4 < 4; ++t4) {
            half2 pa = cvt_pk(__builtin_amdgcn_exp2f(fmaf(st[t4][0], C2, nb)),
                              __builtin_amdgcn_exp2f(fmaf(st[t4][1], C2, nb)));
            half2 pb = cvt_pk(__builtin_amdgcn_exp2f(fmaf(st[t4][2], C2, nb)),
                              __builtin_amdgcn_exp2f(fmaf(st[t4][3], C2, nb)));
            const half4 mv = *(const half4*)(Mh + kv0 + t4 * 16 + lg * 4);
            const half2 mk0 = { mv[0], mv[1] };
            const half2 mk1 = { mv[2], mv[3] };
            pa *= mk0;
            pb *= mk1;
            ps = fdot2_acc(pa, one2, ps);
            ps = fdot2_acc(pb, one2, ps);
            union { half2 hh[2]; half4 v; } pk;
            pk.hh[0] = pa; pk.hh[1] = pb;
            *(half4*)(Pw + lr * 72 + t4 * 16 + lg * 4) = pk.v;
        }
        ps += __shfl_xor(ps, 16);
        ps += __shfl_xor(ps, 32);
        l_run += ps;

        asm volatile("s_waitcnt lgkmcnt(0)" ::: "memory");
        __builtin_amdgcn_sched_barrier(0);

        half8 pf[2];
        pf[0] = *(const half8*)(Pw + lr * 72 + lg * 8);
        pf[1] = *(const half8*)(Pw + lr * 72 + 32 + lg * 8);

        __builtin_amdgcn_s_setprio(1);
        #pragma unroll
        for (int dt = 0; dt < 4; ++dt)
            #pragma unroll
            for (int ks = 0; ks < 2; ++ks) {
                const half8 a = *(const half8*)(Vb + (dt * 16 + lr) * 72 + ks * 32 + lg * 8);
                o[dt] = __builtin_amdgcn_mfma_f32_16x16x32_f16(a, pf[ks], o[dt], 0, 0, 0);
            }
        __builtin_amdgcn_s_setprio(0);
    };

    // 2-deep prefetch: tiles 0,1 in regs before the loop.
    uint4 ka0, ka1, va0, va1, kb0, kb1, vb0, vb1;
    ka0 = *(const uint4*)(Kg);            ka1 = *(const uint4*)(Kg + 8);
    va0 = *(const uint4*)(Vg);            va1 = *(const uint4*)(Vg + 8);
    kb0 = *(const uint4*)(Kg + 64 * 768); kb1 = *(const uint4*)(Kg + 64 * 768 + 8);
    vb0 = *(const uint4*)(Vg + 64);       vb1 = *(const uint4*)(Vg + 64 + 8);

    // Race-freedom: write(tile s -> buf[s&1]) precedes barrier(s); any wave
    // still reading buf[s&1] (tile s-2, during compute(s-2)) cannot have been
    // passed by a wave at write(s), since that wave crossed barrier(s-1) which
    // postdates compute(s-2) in every wave's program order.
    for (int j = 0; j < 8; ++j) {
        // ---- step s = 2j (buf A) ----
        *(uint4*)(KA + pr * 72 + pc)     = ka0;
        *(uint4*)(KA + pr * 72 + pc + 8) = ka1;
        *(uint4*)(VA + pr * 72 + pc)     = va0;
        *(uint4*)(VA + pr * 72 + pc + 8) = va1;
        if (j < 7) {   // load tile 2j+2 into set A
            const int t = (2 * j + 2) * 64;
            ka0 = *(const uint4*)(Kg + t * 768);
            ka1 = *(const uint4*)(Kg + t * 768 + 8);
            va0 = *(const uint4*)(Vg + t);
            va1 = *(const uint4*)(Vg + t + 8);
        }
        __syncthreads();
        compute(2 * j * 64, KA, VA);

        // ---- step s = 2j+1 (buf B) ----
        *(uint4*)(KB + pr * 72 + pc)     = kb0;
        *(uint4*)(KB + pr * 72 + pc + 8) = kb1;
        *(uint4*)(VB + pr * 72 + pc)     = vb0;
        *(uint4*)(VB + pr * 72 + pc + 8) = vb1;
        if (j < 7) {   // load tile 2j+3 into set B
            const int t = (2 * j + 3) * 64;
            kb0 = *(const uint4*)(Kg + t * 768);
            kb1 = *(const uint4*)(Kg + t * 768 + 8);
            vb0 = *(const uint4*)(Vg + t);
            vb1 = *(const uint4*)(Vg + t + 8);
        }
        __syncthreads();
        compute((2 * j + 1) * 64, KB, VB);
    }

    const float inv = 1.f / l_run;
    const int qrow = b * 1024 + q0 + wave * 16 + lr;
    float* od = out + qrow * 768 + h * 64 + lg * 4;
    #pragma unroll
    for (int dt = 0; dt < 4; ++dt) {
        float4 v;
        v.x = o[dt][0] * inv; v.y = o[dt][1] * inv;
        v.z = o[dt][2] * inv; v.w = o[dt][3] * inv;
        *(float4*)(od + dt * 16) = v;
    }
}

extern "C" void kernel_launch(void* const* d_in, const int* in_sizes, int n_in,
                              void* d_out, int out_size, void* d_ws, size_t ws_size,
                              hipStream_t stream)
{
    const float* x  = (const float*)d_in[0];
    const float* y  = (const float*)d_in[1];
    const unsigned char* ym = (const unsigned char*)d_in[2];
    const float* Wq = (const float*)d_in[3];
    const float* bq = (const float*)d_in[4];
    const float* Wk = (const float*)d_in[5];
    const float* bk = (const float*)d_in[6];
    const float* Wv = (const float*)d_in[7];
    const float* bv = (const float*)d_in[8];

    _Float16* kws = (_Float16*)d_ws;             // [8192][768] K
    _Float16* vws = kws + 8192 * 768;            // [B][H*DV][L2] V^T
    _Float16* wt  = vws + 8192 * 768;            // [3][768][768] W^T (q,k,v)
    _Float16* qws = wt + 3 * 768 * 768;          // [8192][768] Q (optional)

    const size_t need = (size_t)(3 * 8192 * 768 + 3 * 768 * 768) * sizeof(_Float16);
    const bool qpre = ws_size >= need;

    wtrans_kernel<<<dim3(24, 24, 3), 256, 0, stream>>>(Wq, Wk, Wv, wt);
    proj_kernel<<<dim3(64, 6, qpre ? 3 : 2), 256, 0, stream>>>(
        x, y, wt, bk, bv, bq, kws, vws, qws);

    dim3 ag(16, 12, 8);
    if (qpre)
        attn_kernel<true><<<ag, 256, 0, stream>>>(x, wt, bq, qws, kws, vws, ym, (float*)d_out);
    else
        attn_kernel<false><<<ag, 256, 0, stream>>>(x, wt, bq, qws, kws, vws, ym, (float*)d_out);
}